// Round 1
// 679.872 us; speedup vs baseline: 1.0013x; 1.0013x over previous
//
#include <hip/hip_runtime.h>

// Problem: N = 1048576 samples, C = 128 classes (layout hard-requires C=128).
// out = ( sum_c |counts_c - colsum_c| - sum_n pred[n, t_n] ) / N
#define NUM_C 128
#define BLOCK_ROWS 512

// Branchless select of pred[row, t] from the thread's float4 (classes 4*c4..4*c4+3).
__device__ __forceinline__ float pick_from(float4 p, int tc) {
    float v = (tc == 0) ? p.x : 0.0f;
    v += (tc == 1) ? p.y : 0.0f;
    v += (tc == 2) ? p.z : 0.0f;
    v += (tc == 3) ? p.w : 0.0f;
    return v;
}

__device__ __forceinline__ void exp_acc(float4& acc, float4 p) {
    acc.x += __expf(p.x);
    acc.y += __expf(p.y);
    acc.z += __expf(p.z);
    acc.w += __expf(p.w);
}

// 256 threads: c4 = tid&31 -> which float4 of the 128-class row; r = tid>>5 ->
// row slot (8 rows per iteration-group). Each wave-wide load is 1 KiB contiguous.
// Epilogue: NO global atomics (atomic contention theory: 2048 co-resident blocks
// hammering the same 257 words serialized ~200us at the coherence point).
// Instead, plain coalesced stores of per-block partials into ws.
__global__ __launch_bounds__(256) void main_pass_kernel(
    const float* __restrict__ pred,   // [N, 128] log-probs
    const int*   __restrict__ tgt,    // [N]
    float* __restrict__ colp,         // [NB, 128] per-block colsum partials
    float* __restrict__ cntp,         // [NB, 128] per-block count partials
    float* __restrict__ pickp,        // [NB]      per-block picked-sum partials
    int N)
{
    const int tid = threadIdx.x;
    const int c4  = tid & 31;
    const int r   = tid >> 5;
    const int row0 = blockIdx.x * BLOCK_ROWS;
    int rows = N - row0; if (rows > BLOCK_ROWS) rows = BLOCK_ROWS;

    __shared__ int s_tgt[BLOCK_ROWS];
    __shared__ int hist[NUM_C];
    for (int i = tid; i < NUM_C; i += 256) hist[i] = 0;
    __syncthreads();

    // Stage targets once; histogram here (out of the hot loop). LDS atomics only
    // (distributed, ~2-way expected collisions) — these are cheap.
    for (int i = tid; i < rows; i += 256) {
        int t = tgt[row0 + i];
        s_tgt[i] = t;
        atomicAdd(&hist[t], 1);
    }
    __syncthreads();

    const float4* __restrict__ p4 = (const float4*)pred + (long long)row0 * (NUM_C / 4) + c4;
    const int base_c = c4 << 2;

    float4 acc = make_float4(0.f, 0.f, 0.f, 0.f);
    float  pick = 0.f;

    // Unroll x4: rows j, j+8, j+16, j+24 -> 4 independent 16B loads in flight.
    int j = r;
    for (; j + 24 < rows; j += 32) {
        float4 a = p4[(j     ) * (NUM_C / 4)];
        float4 b = p4[(j +  8) * (NUM_C / 4)];
        float4 c = p4[(j + 16) * (NUM_C / 4)];
        float4 d = p4[(j + 24) * (NUM_C / 4)];
        int ta = s_tgt[j] - base_c;
        int tb = s_tgt[j +  8] - base_c;
        int tc = s_tgt[j + 16] - base_c;
        int td = s_tgt[j + 24] - base_c;
        exp_acc(acc, a); pick += pick_from(a, ta);
        exp_acc(acc, b); pick += pick_from(b, tb);
        exp_acc(acc, c); pick += pick_from(c, tc);
        exp_acc(acc, d); pick += pick_from(d, td);
    }
    for (; j < rows; j += 8) {   // generic tail (not taken for N=1M)
        float4 a = p4[j * (NUM_C / 4)];
        exp_acc(acc, a);
        pick += pick_from(a, s_tgt[j] - base_c);
    }

    // ---- block-level reduction of per-class sums (8 row-slots -> 1) ----
    __shared__ float s_col[256 * 4];
    s_col[tid * 4 + 0] = acc.x;
    s_col[tid * 4 + 1] = acc.y;
    s_col[tid * 4 + 2] = acc.z;
    s_col[tid * 4 + 3] = acc.w;
    __syncthreads();

    if (tid < NUM_C) {
        int cc4 = tid >> 2, k = tid & 3;
        float s = 0.f;
        #pragma unroll
        for (int rr = 0; rr < 8; ++rr)
            s += s_col[(rr * 32 + cc4) * 4 + k];
        long long o = (long long)blockIdx.x * NUM_C + tid;
        colp[o] = s;                      // plain store, coalesced 512B/block
        cntp[o] = (float)hist[tid];       // plain store
    }

    // ---- picked-sum: wave64 shuffle, then cross-wave via LDS ----
    for (int off = 32; off > 0; off >>= 1)
        pick += __shfl_down(pick, off, 64);
    __shared__ float s_pick[4];
    if ((tid & 63) == 0) s_pick[tid >> 6] = pick;
    __syncthreads();
    if (tid == 0)
        pickp[blockIdx.x] = s_pick[0] + s_pick[1] + s_pick[2] + s_pick[3];
}

// 129 blocks x 256 threads. Blocks 0..127: reduce colp/cntp over NB blocks for
// one class each. Block 128: reduce pickp. Partials total ~2MB -> L2/L3 resident.
__global__ __launch_bounds__(256) void reduce_kernel(
    const float* __restrict__ colp,
    const float* __restrict__ cntp,
    const float* __restrict__ pickp,
    float* __restrict__ g_colsum,
    float* __restrict__ g_counts,
    float* __restrict__ g_pick,
    int nb)
{
    const int c   = blockIdx.x;
    const int tid = threadIdx.x;
    __shared__ float s1[4], s2[4];

    if (c < NUM_C) {
        float sc = 0.f, sn = 0.f;
        for (int b = tid; b < nb; b += 256) {
            long long o = (long long)b * NUM_C + c;
            sc += colp[o];
            sn += cntp[o];
        }
        for (int off = 32; off > 0; off >>= 1) {
            sc += __shfl_down(sc, off, 64);
            sn += __shfl_down(sn, off, 64);
        }
        if ((tid & 63) == 0) { s1[tid >> 6] = sc; s2[tid >> 6] = sn; }
        __syncthreads();
        if (tid == 0) {
            g_colsum[c] = s1[0] + s1[1] + s1[2] + s1[3];
            g_counts[c] = s2[0] + s2[1] + s2[2] + s2[3];
        }
    } else {
        float sp = 0.f;
        for (int b = tid; b < nb; b += 256)
            sp += pickp[b];
        for (int off = 32; off > 0; off >>= 1)
            sp += __shfl_down(sp, off, 64);
        if ((tid & 63) == 0) s1[tid >> 6] = sp;
        __syncthreads();
        if (tid == 0)
            g_pick[0] = s1[0] + s1[1] + s1[2] + s1[3];
    }
}

__global__ void finalize_kernel(const float* __restrict__ g_colsum,
                                const float* __restrict__ g_counts,
                                const float* __restrict__ g_pick,
                                float* __restrict__ out, float invN)
{
    int tid = threadIdx.x;  // 128 threads
    float d = fabsf(g_counts[tid] - g_colsum[tid]);
    for (int off = 32; off > 0; off >>= 1)
        d += __shfl_down(d, off, 64);
    __shared__ float s[2];
    if ((tid & 63) == 0) s[tid >> 6] = d;
    __syncthreads();
    if (tid == 0) out[0] = (s[0] + s[1] - g_pick[0]) * invN;
}

extern "C" void kernel_launch(void* const* d_in, const int* in_sizes, int n_in,
                              void* d_out, int out_size, void* d_ws, size_t ws_size,
                              hipStream_t stream) {
    const float* pred = (const float*)d_in[0];   // [N, C] float32 log-probs
    const int*   tgt  = (const int*)d_in[1];     // [N] int32
    float* out = (float*)d_out;

    const int N  = in_sizes[1];                  // 1048576
    const int NB = (N + BLOCK_ROWS - 1) / BLOCK_ROWS;  // 2048 = 8 blocks/CU

    // ws layout (floats): colp[NB*128] | cntp[NB*128] | pickp[NB] |
    //                     g_colsum[128] | g_counts[128] | g_pick[1]  (~2.06 MB)
    float* ws       = (float*)d_ws;
    float* colp     = ws;
    float* cntp     = colp + (long long)NB * NUM_C;
    float* pickp    = cntp + (long long)NB * NUM_C;
    float* g_colsum = pickp + NB;
    float* g_counts = g_colsum + NUM_C;
    float* g_pick   = g_counts + NUM_C;

    // No init kernel needed: every partial/result slot is written unconditionally.
    main_pass_kernel<<<NB, 256, 0, stream>>>(pred, tgt, colp, cntp, pickp, N);
    reduce_kernel<<<NUM_C + 1, 256, 0, stream>>>(colp, cntp, pickp,
                                                 g_colsum, g_counts, g_pick, NB);
    finalize_kernel<<<1, NUM_C, 0, stream>>>(g_colsum, g_counts, g_pick, out,
                                             1.0f / (float)N);
}